// Round 1
// baseline (572.306 us; speedup 1.0000x reference)
//
#include <hip/hip_runtime.h>
#include <hip/hip_bf16.h>
#include <stdint.h>

#define SEQ    2048
#define DMODEL 4096
#define NH     32
#define NKVH   8
#define HDIM   128
#define KVD    (NKVH*HDIM)   // 1024
#define QD     (NH*HDIM)     // 4096
#define ASCALE 0.08838834764831845f

typedef __attribute__((ext_vector_type(8))) short s8v;   // 8 bf16 = 4 VGPRs
typedef __attribute__((ext_vector_type(4))) float f4v;   // 4 f32 accum

// MFMA via inline asm: avoids builtin operand-type ambiguity; gfx950 unified
// VGPR/AGPR file so v-regs are valid for C/D.
#define MFMA16(acc, a, b) \
  asm("v_mfma_f32_16x16x32_bf16 %0, %1, %2, %0" : "+v"(acc) : "v"(a), "v"(b))

__device__ __forceinline__ void gl2lds16(const void* g, void* l) {
  __builtin_amdgcn_global_load_lds(
      (const __attribute__((address_space(1))) void*)g,
      (__attribute__((address_space(3))) void*)l, 16, 0, 0);
}

__device__ __forceinline__ void store_out(__hip_bfloat16* p, float v) { *p = __float2bfloat16(v); }
__device__ __forceinline__ void store_out(float* p, float v) { *p = v; }

// ---------------- f32 -> bf16 convert (8 elems/thread) ----------------
__global__ __launch_bounds__(256) void k_cvt(const float* __restrict__ in,
                                             __hip_bfloat16* __restrict__ out, int n8) {
  int i = blockIdx.x * 256 + threadIdx.x;
  if (i >= n8) return;
  const float4* p = (const float4*)in + (size_t)i * 2;
  float4 a = p[0], b = p[1];
  union { __hip_bfloat16 h[8]; s8v v; } o;
  o.h[0] = __float2bfloat16(a.x); o.h[1] = __float2bfloat16(a.y);
  o.h[2] = __float2bfloat16(a.z); o.h[3] = __float2bfloat16(a.w);
  o.h[4] = __float2bfloat16(b.x); o.h[5] = __float2bfloat16(b.y);
  o.h[6] = __float2bfloat16(b.z); o.h[7] = __float2bfloat16(b.w);
  *(s8v*)(out + (size_t)i * 8) = o.v;
}

// ---------------- RoPE in-place on bf16 (one (re,im) pair per thread) ----------------
__global__ __launch_bounds__(256) void k_rope(__hip_bfloat16* __restrict__ t,
                                              const float* __restrict__ fc,
                                              const float* __restrict__ fs, int heads) {
  int pid = blockIdx.x * 256 + threadIdx.x;
  int i = pid & 63;
  int rest = pid >> 6;
  int h = rest % heads;
  int s = rest / heads;
  size_t base = ((size_t)s * heads + h) * HDIM + 2 * i;
  uint32_t u = *(const uint32_t*)(t + base);
  __hip_bfloat16 hh[2]; *(uint32_t*)hh = u;
  float tr = __bfloat162float(hh[0]), ti = __bfloat162float(hh[1]);
  float c = fc[(size_t)s * 64 + i], sv = fs[(size_t)s * 64 + i];
  hh[0] = __float2bfloat16(tr * c - ti * sv);
  hh[1] = __float2bfloat16(tr * sv + ti * c);
  *(uint32_t*)(t + base) = *(uint32_t*)hh;
}

// ---------------- C = A(M,K) * B(N,K)^T, bf16 in, OT out ----------------
// m97 structure: 128x128 tile, BK=64, 4 waves (2x2), 4x4 16x16x32 frags/wave.
// T2 XOR swizzle applied via pre-swizzled global source (rule #21: linear LDS
// dest + inverse-swz source + swz read; XOR is its own inverse).
template <typename OT>
__global__ __launch_bounds__(256) void k_gemm_bt(const __hip_bfloat16* __restrict__ A,
                                                 const __hip_bfloat16* __restrict__ B,
                                                 OT* __restrict__ C, int M, int N, int K) {
  __shared__ __align__(16) __hip_bfloat16 As[128 * 64];
  __shared__ __align__(16) __hip_bfloat16 Bs[128 * 64];
  const int t = threadIdx.x;
  const int wave = t >> 6, lane = t & 63;
  const int lrow = lane & 15, kq = lane >> 4;
  const int wr = wave >> 1, wc = wave & 1;
  const int m0 = blockIdx.y * 128, n0 = blockIdx.x * 128;

  f4v acc[4][4] = {};

  for (int k0 = 0; k0 < K; k0 += 64) {
    // stage 128x64 A and B tiles; row = 64 elems = 8 chunks of 16B
#pragma unroll
    for (int it = 0; it < 4; ++it) {
      int chunk = it * 256 + t;
      int r = chunk >> 3;
      int cc = ((chunk & 7) ^ (r & 7)) * 8;
      gl2lds16(A + (size_t)(m0 + r) * K + k0 + cc, (char*)As + it * 4096 + wave * 1024);
      gl2lds16(B + (size_t)(n0 + r) * K + k0 + cc, (char*)Bs + it * 4096 + wave * 1024);
    }
    __syncthreads();  // drains vmcnt(0) -> staging complete
#pragma unroll
    for (int kk = 0; kk < 64; kk += 32) {
      s8v af[4], bfr[4];
#pragma unroll
      for (int m = 0; m < 4; ++m) {
        int row = wr * 64 + m * 16 + lrow;
        af[m] = *(const s8v*)&As[row * 64 + ((kk + kq * 8) ^ ((row & 7) << 3))];
      }
#pragma unroll
      for (int n = 0; n < 4; ++n) {
        int row = wc * 64 + n * 16 + lrow;
        bfr[n] = *(const s8v*)&Bs[row * 64 + ((kk + kq * 8) ^ ((row & 7) << 3))];
      }
#pragma unroll
      for (int m = 0; m < 4; ++m)
#pragma unroll
        for (int n = 0; n < 4; ++n)
          MFMA16(acc[m][n], af[m], bfr[n]);
    }
    __syncthreads();
  }

  // C/D layout (m89-verified): col = lane&15, row = (lane>>4)*4 + j
#pragma unroll
  for (int m = 0; m < 4; ++m)
#pragma unroll
    for (int n = 0; n < 4; ++n)
#pragma unroll
      for (int j = 0; j < 4; ++j) {
        int r = m0 + wr * 64 + m * 16 + kq * 4 + j;
        int c = n0 + wc * 64 + n * 16 + lrow;
        store_out(&C[(size_t)r * N + c], acc[m][n][j]);
      }
}

// ---------------- causal flash attention, bf16 MFMA ----------------
// Block: 4 waves, one (head, 64 q-rows). Wave w owns q rows q0+16w..+16.
__global__ __launch_bounds__(256) void k_flash(const __hip_bfloat16* __restrict__ Q,
                                               const __hip_bfloat16* __restrict__ Kb,
                                               const __hip_bfloat16* __restrict__ Vb,
                                               __hip_bfloat16* __restrict__ O) {
  __shared__ __align__(16) __hip_bfloat16 Ks[64 * 128];    // K tile, swizzled
  __shared__ __align__(16) __hip_bfloat16 Vt[128 * 64];    // V^T tile, swizzled
  __shared__ __align__(16) __hip_bfloat16 Ps[4][16 * 64];  // per-wave P buffer
  const int qt = blockIdx.x, h = blockIdx.y, g = h >> 2;   // GQA: 4 q-heads / kv-head
  const int t = threadIdx.x, wave = t >> 6, lane = t & 63;
  const int lrow = lane & 15, kq = lane >> 4;
  const int q0 = qt * 64;
  const int qrow = q0 + wave * 16 + lrow;

  // Q fragments in registers: A-frag row = lane&15, k = tt*32 + kq*8 + j
  s8v qf[4];
#pragma unroll
  for (int tt = 0; tt < 4; ++tt)
    qf[tt] = *(const s8v*)(Q + (size_t)qrow * QD + h * HDIM + tt * 32 + kq * 8);

  f4v acc_o[8] = {};
  float mrun[4] = {-1e30f, -1e30f, -1e30f, -1e30f};
  float lrun[4] = {0.f, 0.f, 0.f, 0.f};

  const int nt = qt + 1;  // causal: kv tiles 0..qt
  for (int kvt = 0; kvt < nt; ++kvt) {
    const int kv = kvt * 64;
    // stage K (64x128), linear LDS + inverse-swizzled source
#pragma unroll
    for (int it = 0; it < 4; ++it) {
      int chunk = it * 256 + t;
      int r = chunk >> 4;
      int cc = ((chunk & 15) ^ (r & 7)) * 8;
      gl2lds16(Kb + (size_t)(kv + r) * KVD + g * HDIM + cc, (char*)Ks + it * 4096 + wave * 1024);
    }
    // stage V transposed (coalesced global read, scattered swizzled LDS write)
#pragma unroll
    for (int it = 0; it < 4; ++it) {
      int chunk = it * 256 + t;
      int kvr = chunk >> 4;
      int d0 = (chunk & 15) * 8;
      s8v v = *(const s8v*)(Vb + (size_t)(kv + kvr) * KVD + g * HDIM + d0);
      const __hip_bfloat16* vh = (const __hip_bfloat16*)&v;
#pragma unroll
      for (int e = 0; e < 8; ++e) {
        int d = d0 + e;
        Vt[d * 64 + (kvr ^ (((d >> 3) & 7) << 3))] = vh[e];
      }
    }
    __syncthreads();

    // S = Q * K^T   (16 q x 64 k per wave)
    f4v accs[4] = {};
#pragma unroll
    for (int tt = 0; tt < 4; ++tt)
#pragma unroll
      for (int n = 0; n < 4; ++n) {
        int row = n * 16 + lrow;
        s8v bfr = *(const s8v*)&Ks[row * 128 + ((tt * 32 + kq * 8) ^ ((row & 7) << 3))];
        MFMA16(accs[n], qf[tt], bfr);
      }

    // online softmax; output rows live on 16-lane groups (same lane>>4)
    float pv[4][4];
#pragma unroll
    for (int j = 0; j < 4; ++j) {
      const int qi = q0 + wave * 16 + kq * 4 + j;
      float mx = -1e30f;
#pragma unroll
      for (int n = 0; n < 4; ++n) {
        int ki = kv + n * 16 + lrow;
        float val = (ki <= qi) ? accs[n][j] * ASCALE : -1e30f;
        pv[n][j] = val;
        mx = fmaxf(mx, val);
      }
#pragma unroll
      for (int msk = 1; msk < 16; msk <<= 1)
        mx = fmaxf(mx, __shfl_xor(mx, msk, 64));
      float mnew = fmaxf(mrun[j], mx);
      float fsc = __expf(mrun[j] - mnew);
      mrun[j] = mnew;
      float rs = 0.f;
#pragma unroll
      for (int n = 0; n < 4; ++n) {
        float p = __expf(pv[n][j] - mnew);
        pv[n][j] = p;
        rs += p;
      }
#pragma unroll
      for (int msk = 1; msk < 16; msk <<= 1)
        rs += __shfl_xor(rs, msk, 64);
      lrun[j] = lrun[j] * fsc + rs;
#pragma unroll
      for (int n = 0; n < 8; ++n) acc_o[n][j] *= fsc;
    }

    // P: C/D layout -> LDS (swizzled) -> A-frag layout. Per-wave buffer.
#pragma unroll
    for (int j = 0; j < 4; ++j) {
      int drow = kq * 4 + j;
#pragma unroll
      for (int n = 0; n < 4; ++n) {
        int kcol = n * 16 + lrow;
        Ps[wave][drow * 64 + (kcol ^ ((drow & 7) << 3))] = __float2bfloat16(pv[n][j]);
      }
    }
    asm volatile("" ::: "memory");  // defeat TBAA write/read reordering

    // O += P(16x64) * V(64x128); B-operand from Vt rows (d-major)
#pragma unroll
    for (int tt = 0; tt < 2; ++tt) {
      s8v pa = *(const s8v*)&Ps[wave][lrow * 64 + ((tt * 32 + kq * 8) ^ ((lrow & 7) << 3))];
#pragma unroll
      for (int n = 0; n < 8; ++n) {
        int d = n * 16 + lrow;
        s8v bfr = *(const s8v*)&Vt[d * 64 + ((tt * 32 + kq * 8) ^ (((d >> 3) & 7) << 3))];
        MFMA16(acc_o[n], pa, bfr);
      }
    }
    __syncthreads();
  }

#pragma unroll
  for (int n = 0; n < 8; ++n)
#pragma unroll
    for (int j = 0; j < 4; ++j) {
      int qi = q0 + wave * 16 + kq * 4 + j;
      int d = n * 16 + lrow;
      O[(size_t)qi * QD + h * HDIM + d] = __float2bfloat16(acc_o[n][j] / lrun[j]);
    }
}

// ---------------- launch ----------------
extern "C" void kernel_launch(void* const* d_in, const int* in_sizes, int n_in,
                              void* d_out, int out_size, void* d_ws, size_t ws_size,
                              hipStream_t stream) {
  const float* x  = (const float*)d_in[0];
  const float* fc = (const float*)d_in[1];
  const float* fs = (const float*)d_in[2];
  const float* wq = (const float*)d_in[3];
  const float* wk = (const float*)d_in[4];
  const float* wv = (const float*)d_in[5];
  const float* wo = (const float*)d_in[6];
  // d_in[7] mask (pure causal here: WIN==S), d_in[8] positions: unused
  float* out = (float*)d_out;

  char* ws = (char*)d_ws;
  auto alloc = [&](size_t bytes) {
    char* p = ws;
    ws += (bytes + 255) & ~(size_t)255;
    return p;
  };
  __hip_bfloat16* xb  = (__hip_bfloat16*)alloc((size_t)SEQ * DMODEL * 2);
  __hip_bfloat16* wqb = (__hip_bfloat16*)alloc((size_t)QD * DMODEL * 2);
  __hip_bfloat16* wkb = (__hip_bfloat16*)alloc((size_t)KVD * DMODEL * 2);
  __hip_bfloat16* wvb = (__hip_bfloat16*)alloc((size_t)KVD * DMODEL * 2);
  __hip_bfloat16* wob = (__hip_bfloat16*)alloc((size_t)DMODEL * QD * 2);
  __hip_bfloat16* Qb  = (__hip_bfloat16*)alloc((size_t)SEQ * QD * 2);
  __hip_bfloat16* Kc  = (__hip_bfloat16*)alloc((size_t)SEQ * KVD * 2);
  __hip_bfloat16* Vc  = (__hip_bfloat16*)alloc((size_t)SEQ * KVD * 2);
  __hip_bfloat16* Ob  = (__hip_bfloat16*)alloc((size_t)SEQ * QD * 2);

  auto cvt = [&](const float* src, __hip_bfloat16* dst, size_t n) {
    int n8 = (int)(n / 8);
    k_cvt<<<dim3((n8 + 255) / 256), dim3(256), 0, stream>>>(src, dst, n8);
  };
  cvt(x,  xb,  (size_t)SEQ * DMODEL);
  cvt(wq, wqb, (size_t)QD * DMODEL);
  cvt(wk, wkb, (size_t)KVD * DMODEL);
  cvt(wv, wvb, (size_t)KVD * DMODEL);
  cvt(wo, wob, (size_t)DMODEL * QD);

  k_gemm_bt<__hip_bfloat16><<<dim3(QD / 128, SEQ / 128), 256, 0, stream>>>(xb, wqb, Qb, SEQ, QD, DMODEL);
  k_gemm_bt<__hip_bfloat16><<<dim3(KVD / 128, SEQ / 128), 256, 0, stream>>>(xb, wkb, Kc, SEQ, KVD, DMODEL);
  k_gemm_bt<__hip_bfloat16><<<dim3(KVD / 128, SEQ / 128), 256, 0, stream>>>(xb, wvb, Vc, SEQ, KVD, DMODEL);

  k_rope<<<dim3(SEQ * NH * 64 / 256), 256, 0, stream>>>(Qb, fc, fs, NH);
  k_rope<<<dim3(SEQ * NKVH * 64 / 256), 256, 0, stream>>>(Kc, fc, fs, NKVH);

  k_flash<<<dim3(SEQ / 64, NH), 256, 0, stream>>>(Qb, Kc, Vc, Ob);

  k_gemm_bt<float><<<dim3(DMODEL / 128, SEQ / 128), 256, 0, stream>>>(Ob, wob, out, SEQ, DMODEL, DMODEL);
}

// Round 3
// 355.217 us; speedup vs baseline: 1.6111x; 1.6111x over previous
//
#include <hip/hip_runtime.h>
#include <hip/hip_bf16.h>
#include <stdint.h>

#define SEQ    2048
#define DMODEL 4096
#define NH     32
#define NKVH   8
#define HDIM   128
#define KVD    (NKVH*HDIM)   // 1024
#define QD     (NH*HDIM)     // 4096
#define ASCALE 0.08838834764831845f

typedef __attribute__((ext_vector_type(8))) short s8v;   // 8 bf16
typedef __attribute__((ext_vector_type(4))) short s4v;   // 4 bf16
typedef __attribute__((ext_vector_type(4))) float f4v;   // 4 f32

#define MFMA16(acc, a, b) \
  asm("v_mfma_f32_16x16x32_bf16 %0, %1, %2, %0" : "+v"(acc) : "v"(a), "v"(b))

__device__ __forceinline__ void gl2lds16(const void* g, void* l) {
  __builtin_amdgcn_global_load_lds(
      (const __attribute__((address_space(1))) void*)g,
      (__attribute__((address_space(3))) void*)l, 16, 0, 0);
}

__device__ __forceinline__ void store_out(__hip_bfloat16* p, float v) { *p = __float2bfloat16(v); }
__device__ __forceinline__ void store_out(float* p, float v) { *p = v; }

// ---------------- f32 -> bf16 convert ----------------
__global__ __launch_bounds__(256) void k_cvt(const float* __restrict__ in,
                                             __hip_bfloat16* __restrict__ out, int n8) {
  int i = blockIdx.x * 256 + threadIdx.x;
  if (i >= n8) return;
  const float4* p = (const float4*)in + (size_t)i * 2;
  float4 a = p[0], b = p[1];
  union { __hip_bfloat16 h[8]; s8v v; } o;
  o.h[0] = __float2bfloat16(a.x); o.h[1] = __float2bfloat16(a.y);
  o.h[2] = __float2bfloat16(a.z); o.h[3] = __float2bfloat16(a.w);
  o.h[4] = __float2bfloat16(b.x); o.h[5] = __float2bfloat16(b.y);
  o.h[6] = __float2bfloat16(b.z); o.h[7] = __float2bfloat16(b.w);
  *(s8v*)(out + (size_t)i * 8) = o.v;
}

// ---------------- RoPE in-place on bf16 ----------------
__global__ __launch_bounds__(256) void k_rope(__hip_bfloat16* __restrict__ t,
                                              const float* __restrict__ fc,
                                              const float* __restrict__ fs, int heads) {
  int pid = blockIdx.x * 256 + threadIdx.x;
  int i = pid & 63;
  int rest = pid >> 6;
  int h = rest % heads;
  int s = rest / heads;
  size_t base = ((size_t)s * heads + h) * HDIM + 2 * i;
  uint32_t u = *(const uint32_t*)(t + base);
  __hip_bfloat16 hh[2]; *(uint32_t*)hh = u;
  float tr = __bfloat162float(hh[0]), ti = __bfloat162float(hh[1]);
  float c = fc[(size_t)s * 64 + i], sv = fs[(size_t)s * 64 + i];
  hh[0] = __float2bfloat16(tr * c - ti * sv);
  hh[1] = __float2bfloat16(tr * sv + ti * c);
  *(uint32_t*)(t + base) = *(uint32_t*)hh;
}

// ---------------- C = A(M,K) * B(N,K)^T (m97 structure, verified R1) ----------------
template <typename OT>
__global__ __launch_bounds__(256) void k_gemm_bt(const __hip_bfloat16* __restrict__ A,
                                                 const __hip_bfloat16* __restrict__ B,
                                                 OT* __restrict__ C, int M, int N, int K) {
  __shared__ __align__(16) __hip_bfloat16 As[128 * 64];
  __shared__ __align__(16) __hip_bfloat16 Bs[128 * 64];
  const int t = threadIdx.x;
  const int wave = t >> 6, lane = t & 63;
  const int lrow = lane & 15, kq = lane >> 4;
  const int wr = wave >> 1, wc = wave & 1;
  const int m0 = blockIdx.y * 128, n0 = blockIdx.x * 128;

  f4v acc[4][4] = {};

  for (int k0 = 0; k0 < K; k0 += 64) {
#pragma unroll
    for (int it = 0; it < 4; ++it) {
      int chunk = it * 256 + t;
      int r = chunk >> 3;
      int cc = ((chunk & 7) ^ (r & 7)) * 8;
      gl2lds16(A + (size_t)(m0 + r) * K + k0 + cc, (char*)As + it * 4096 + wave * 1024);
      gl2lds16(B + (size_t)(n0 + r) * K + k0 + cc, (char*)Bs + it * 4096 + wave * 1024);
    }
    __syncthreads();
#pragma unroll
    for (int kk = 0; kk < 64; kk += 32) {
      s8v af[4], bfr[4];
#pragma unroll
      for (int m = 0; m < 4; ++m) {
        int row = wr * 64 + m * 16 + lrow;
        af[m] = *(const s8v*)&As[row * 64 + ((kk + kq * 8) ^ ((row & 7) << 3))];
      }
#pragma unroll
      for (int n = 0; n < 4; ++n) {
        int row = wc * 64 + n * 16 + lrow;
        bfr[n] = *(const s8v*)&Bs[row * 64 + ((kk + kq * 8) ^ ((row & 7) << 3))];
      }
#pragma unroll
      for (int m = 0; m < 4; ++m)
#pragma unroll
        for (int n = 0; n < 4; ++n)
          MFMA16(acc[m][n], af[m], bfr[n]);
    }
    __syncthreads();
  }

#pragma unroll
  for (int m = 0; m < 4; ++m)
#pragma unroll
    for (int n = 0; n < 4; ++n)
#pragma unroll
      for (int j = 0; j < 4; ++j) {
        int r = m0 + wr * 64 + m * 16 + kq * 4 + j;
        int c = n0 + wc * 64 + n * 16 + lrow;
        store_out(&C[(size_t)r * N + c], acc[m][n][j]);
      }
}

// ---------------- fused K+V projection: K row-major, V transposed (d-major) ----------------
__global__ __launch_bounds__(256) void k_gemm_kv(const __hip_bfloat16* __restrict__ A,
                                                 const __hip_bfloat16* __restrict__ Bk,
                                                 const __hip_bfloat16* __restrict__ Bv,
                                                 __hip_bfloat16* __restrict__ Ck,
                                                 __hip_bfloat16* __restrict__ Vt) {
  __shared__ __align__(16) __hip_bfloat16 As[128 * 64];
  __shared__ __align__(16) __hip_bfloat16 Bs[128 * 64];
  const int t = threadIdx.x;
  const int wave = t >> 6, lane = t & 63;
  const int lrow = lane & 15, kq = lane >> 4;
  const int wr = wave >> 1, wc = wave & 1;
  const int m0 = blockIdx.y * 128;
  const bool isV = blockIdx.x >= 8;
  const int n0 = (blockIdx.x & 7) * 128;
  const __hip_bfloat16* B = isV ? Bv : Bk;

  f4v acc[4][4] = {};

  for (int k0 = 0; k0 < DMODEL; k0 += 64) {
#pragma unroll
    for (int it = 0; it < 4; ++it) {
      int chunk = it * 256 + t;
      int r = chunk >> 3;
      int cc = ((chunk & 7) ^ (r & 7)) * 8;
      gl2lds16(A + (size_t)(m0 + r) * DMODEL + k0 + cc, (char*)As + it * 4096 + wave * 1024);
      gl2lds16(B + (size_t)(n0 + r) * DMODEL + k0 + cc, (char*)Bs + it * 4096 + wave * 1024);
    }
    __syncthreads();
#pragma unroll
    for (int kk = 0; kk < 64; kk += 32) {
      s8v af[4], bfr[4];
#pragma unroll
      for (int m = 0; m < 4; ++m) {
        int row = wr * 64 + m * 16 + lrow;
        af[m] = *(const s8v*)&As[row * 64 + ((kk + kq * 8) ^ ((row & 7) << 3))];
      }
#pragma unroll
      for (int n = 0; n < 4; ++n) {
        int row = wc * 64 + n * 16 + lrow;
        bfr[n] = *(const s8v*)&Bs[row * 64 + ((kk + kq * 8) ^ ((row & 7) << 3))];
      }
#pragma unroll
      for (int m = 0; m < 4; ++m)
#pragma unroll
        for (int n = 0; n < 4; ++n)
          MFMA16(acc[m][n], af[m], bfr[n]);
    }
    __syncthreads();
  }

  if (isV) {
    // transposed write: Vt[kv-dim c][s], 4 consecutive s per lane -> 8B stores
#pragma unroll
    for (int m = 0; m < 4; ++m)
#pragma unroll
      for (int n = 0; n < 4; ++n) {
        int c = n0 + wc * 64 + n * 16 + lrow;
        int r0 = m0 + wr * 64 + m * 16 + kq * 4;
        union { __hip_bfloat16 b[4]; s4v v; } u;
#pragma unroll
        for (int j = 0; j < 4; ++j) u.b[j] = __float2bfloat16(acc[m][n][j]);
        *(s4v*)&Vt[(size_t)c * SEQ + r0] = u.v;
      }
  } else {
#pragma unroll
    for (int m = 0; m < 4; ++m)
#pragma unroll
      for (int n = 0; n < 4; ++n)
#pragma unroll
        for (int j = 0; j < 4; ++j) {
          int r = m0 + wr * 64 + m * 16 + kq * 4 + j;
          int c = n0 + wc * 64 + n * 16 + lrow;
          Ck[(size_t)r * KVD + c] = __float2bfloat16(acc[m][n][j]);
        }
  }
}

// ---------------- causal flash attention ----------------
// Block: 4 waves, one head, TWO paired q-tiles (qp, 31-qp) -> constant 33 tile-units.
// K double-buffered, V staged from pre-transposed global. R1-exact softmax numerics.
__global__ __launch_bounds__(256, 2) void k_flash(const __hip_bfloat16* __restrict__ Q,
                                                  const __hip_bfloat16* __restrict__ Kb,
                                                  const __hip_bfloat16* __restrict__ Vtg,
                                                  __hip_bfloat16* __restrict__ O) {
  __shared__ __align__(16) __hip_bfloat16 Ks[2][64 * 128];
  __shared__ __align__(16) __hip_bfloat16 Vs[128 * 64];
  __shared__ __align__(16) __hip_bfloat16 Ps[4][16 * 64];
  const int qp = blockIdx.x, h = blockIdx.y, g = h >> 2;
  const int t = threadIdx.x, wave = t >> 6, lane = t & 63;
  const int lrow = lane & 15, kq = lane >> 4;
  const int qtA = qp, qtB = 31 - qp;

  s8v qfA[4], qfB[4];
  {
    const int qrA = qtA * 64 + wave * 16 + lrow;
    const int qrB = qtB * 64 + wave * 16 + lrow;
#pragma unroll
    for (int tt = 0; tt < 4; ++tt) {
      qfA[tt] = *(const s8v*)(Q + (size_t)qrA * QD + h * HDIM + tt * 32 + kq * 8);
      qfB[tt] = *(const s8v*)(Q + (size_t)qrB * QD + h * HDIM + tt * 32 + kq * 8);
    }
  }

  f4v oA[8] = {}, oB[8] = {};
  float mA[4], lA[4], mB[4], lB[4];
#pragma unroll
  for (int j = 0; j < 4; ++j) { mA[j] = mB[j] = -1e30f; lA[j] = lB[j] = 0.f; }

  auto stage_k = [&](int buf, int kv) {
#pragma unroll
    for (int it = 0; it < 4; ++it) {
      int chunk = it * 256 + t;
      int r = chunk >> 4, cc = ((chunk & 15) ^ (r & 7)) * 8;
      gl2lds16(Kb + (size_t)(kv * 64 + r) * KVD + g * HDIM + cc,
               (char*)&Ks[buf][0] + it * 4096 + wave * 1024);
    }
  };
  auto stage_v = [&](int kv) {
#pragma unroll
    for (int it = 0; it < 4; ++it) {
      int chunk = it * 256 + t;
      int d = chunk >> 3, cc = ((chunk & 7) ^ (d & 7)) * 8;
      gl2lds16(Vtg + (size_t)(g * HDIM + d) * SEQ + kv * 64 + cc,
               (char*)Vs + it * 4096 + wave * 1024);
    }
  };

  // R1-exact softmax + PV for one q-tile job
  auto soft_pv = [&](f4v (&s)[4], int qt, int kv, f4v (&acc_o)[8], float (&mrun)[4],
                     float (&lrun)[4]) {
    __hip_bfloat16* P = &Ps[wave][0];
    asm volatile("" ::: "memory");
#pragma unroll
    for (int j = 0; j < 4; ++j) {
      const int qi = qt * 64 + wave * 16 + kq * 4 + j;
      float p4[4];
      float mx = -1e30f;
#pragma unroll
      for (int n = 0; n < 4; ++n) {
        int ki = kv * 64 + n * 16 + lrow;
        float v = (ki <= qi) ? s[n][j] * ASCALE : -1e30f;
        p4[n] = v;
        mx = fmaxf(mx, v);
      }
#pragma unroll
      for (int msk = 1; msk < 16; msk <<= 1) mx = fmaxf(mx, __shfl_xor(mx, msk, 64));
      float mnew = fmaxf(mrun[j], mx);
      float fsc = __expf(mrun[j] - mnew);
      mrun[j] = mnew;
      float rs = 0.f;
      const int drow = kq * 4 + j;
#pragma unroll
      for (int n = 0; n < 4; ++n) {
        float p = __expf(p4[n] - mnew);
        rs += p;
        P[drow * 64 + ((n * 16 + lrow) ^ ((drow & 7) << 3))] = __float2bfloat16(p);
      }
#pragma unroll
      for (int msk = 1; msk < 16; msk <<= 1) rs += __shfl_xor(rs, msk, 64);
      lrun[j] = lrun[j] * fsc + rs;
#pragma unroll
      for (int n = 0; n < 8; ++n) acc_o[n][j] *= fsc;
    }
    asm volatile("" ::: "memory");
#pragma unroll
    for (int tt = 0; tt < 2; ++tt) {
      s8v pa = *(const s8v*)&P[lrow * 64 + ((tt * 32 + kq * 8) ^ ((lrow & 7) << 3))];
#pragma unroll
      for (int n = 0; n < 8; ++n) {
        int d = n * 16 + lrow;
        s8v vf = *(const s8v*)&Vs[d * 64 + ((tt * 32 + kq * 8) ^ ((d & 7) << 3))];
        MFMA16(acc_o[n], pa, vf);
      }
    }
  };

  stage_k(0, 0);
  int cur = 0;
  for (int kv = 0; kv <= qtB; ++kv) {
    const bool actA = (kv <= qtA);
    __syncthreads();                  // K[cur]+V reads of prior iter done; K[cur] staged
    if (kv < qtB) stage_k(cur ^ 1, kv + 1);
    stage_v(kv);

    f4v sB[4] = {}, sA[4] = {};
    if (actA) {
#pragma unroll
      for (int tt = 0; tt < 4; ++tt)
#pragma unroll
        for (int n = 0; n < 4; ++n) {
          int row = n * 16 + lrow;
          s8v kf = *(const s8v*)&Ks[cur][row * 128 + ((tt * 32 + kq * 8) ^ ((row & 7) << 3))];
          MFMA16(sB[n], qfB[tt], kf);
          MFMA16(sA[n], qfA[tt], kf);
        }
    } else {
#pragma unroll
      for (int tt = 0; tt < 4; ++tt)
#pragma unroll
        for (int n = 0; n < 4; ++n) {
          int row = n * 16 + lrow;
          s8v kf = *(const s8v*)&Ks[cur][row * 128 + ((tt * 32 + kq * 8) ^ ((row & 7) << 3))];
          MFMA16(sB[n], qfB[tt], kf);
        }
    }
    __syncthreads();                  // Vs(kv) staged (vmcnt drained)

    soft_pv(sB, qtB, kv, oB, mB, lB);
    if (actA) soft_pv(sA, qtA, kv, oA, mA, lA);
    cur ^= 1;
  }

#pragma unroll
  for (int n = 0; n < 8; ++n)
#pragma unroll
    for (int j = 0; j < 4; ++j) {
      int d = n * 16 + lrow;
      int qiB = qtB * 64 + wave * 16 + kq * 4 + j;
      O[(size_t)qiB * QD + h * HDIM + d] = __float2bfloat16(oB[n][j] / lB[j]);
      int qiA = qtA * 64 + wave * 16 + kq * 4 + j;
      O[(size_t)qiA * QD + h * HDIM + d] = __float2bfloat16(oA[n][j] / lA[j]);
    }
}

// ---------------- launch ----------------
extern "C" void kernel_launch(void* const* d_in, const int* in_sizes, int n_in,
                              void* d_out, int out_size, void* d_ws, size_t ws_size,
                              hipStream_t stream) {
  const float* x  = (const float*)d_in[0];
  const float* fc = (const float*)d_in[1];
  const float* fs = (const float*)d_in[2];
  const float* wq = (const float*)d_in[3];
  const float* wk = (const float*)d_in[4];
  const float* wv = (const float*)d_in[5];
  const float* wo = (const float*)d_in[6];
  float* out = (float*)d_out;

  char* ws = (char*)d_ws;
  auto alloc = [&](size_t bytes) {
    char* p = ws;
    ws += (bytes + 255) & ~(size_t)255;
    return p;
  };
  __hip_bfloat16* xb  = (__hip_bfloat16*)alloc((size_t)SEQ * DMODEL * 2);
  __hip_bfloat16* wqb = (__hip_bfloat16*)alloc((size_t)QD * DMODEL * 2);
  __hip_bfloat16* wkb = (__hip_bfloat16*)alloc((size_t)KVD * DMODEL * 2);
  __hip_bfloat16* wvb = (__hip_bfloat16*)alloc((size_t)KVD * DMODEL * 2);
  __hip_bfloat16* wob = (__hip_bfloat16*)alloc((size_t)DMODEL * QD * 2);
  __hip_bfloat16* Qb  = (__hip_bfloat16*)alloc((size_t)SEQ * QD * 2);
  __hip_bfloat16* Kc  = (__hip_bfloat16*)alloc((size_t)SEQ * KVD * 2);
  __hip_bfloat16* Vtg = (__hip_bfloat16*)alloc((size_t)KVD * SEQ * 2);
  __hip_bfloat16* Ob  = (__hip_bfloat16*)alloc((size_t)SEQ * QD * 2);

  auto cvt = [&](const float* src, __hip_bfloat16* dst, size_t n) {
    int n8 = (int)(n / 8);
    k_cvt<<<dim3((n8 + 255) / 256), dim3(256), 0, stream>>>(src, dst, n8);
  };
  cvt(x,  xb,  (size_t)SEQ * DMODEL);
  cvt(wq, wqb, (size_t)QD * DMODEL);
  cvt(wk, wkb, (size_t)KVD * DMODEL);
  cvt(wv, wvb, (size_t)KVD * DMODEL);
  cvt(wo, wob, (size_t)DMODEL * QD);

  k_gemm_bt<__hip_bfloat16><<<dim3(QD / 128, SEQ / 128), 256, 0, stream>>>(xb, wqb, Qb, SEQ, QD, DMODEL);
  k_gemm_kv<<<dim3(16, SEQ / 128), 256, 0, stream>>>(xb, wkb, wvb, Kc, Vtg);

  k_rope<<<dim3(SEQ * NH * 64 / 256), 256, 0, stream>>>(Qb, fc, fs, NH);
  k_rope<<<dim3(SEQ * NKVH * 64 / 256), 256, 0, stream>>>(Kc, fc, fs, NKVH);

  k_flash<<<dim3(16, NH), 256, 0, stream>>>(Qb, Kc, Vtg, Ob);

  k_gemm_bt<float><<<dim3(DMODEL / 128, SEQ / 128), 256, 0, stream>>>(Ob, wob, out, SEQ, DMODEL, DMODEL);
}